// Round 5
// baseline (131.840 us; speedup 1.0000x reference)
//
#include <hip/hip_runtime.h>
#include <hip/hip_bf16.h>

#define N0C 100000
#define N1C 50000
#define N2C 25000

typedef _Float16 f16;
typedef _Float16 f16x2 __attribute__((ext_vector_type(2)));
typedef _Float16 f16x4 __attribute__((ext_vector_type(4)));
typedef _Float16 f16x8 __attribute__((ext_vector_type(8)));
typedef float f32x16 __attribute__((ext_vector_type(16)));

// ---------------------------------------------------------------- prep1 -----
// e1[k][4] = {Ws1[:,0:128]@as1_h0, Ws1[:,128:]@as1_h1, Wd1[:,0:128]@ad1_h0, Wd1[:,128:]@ad1_h1}
// e2[k][2] = {Ws2@as2, Wd2@ad2};  bns/bnt = folded BN scale/shift
__global__ void prep1_kernel(const float* __restrict__ Ws1, const float* __restrict__ Wd1,
                             const float* __restrict__ as1, const float* __restrict__ ad1,
                             const float* __restrict__ Ws2, const float* __restrict__ Wd2,
                             const float* __restrict__ as2, const float* __restrict__ ad2,
                             const float* __restrict__ b1, const float* __restrict__ g1,
                             const float* __restrict__ beta1, const float* __restrict__ m1,
                             const float* __restrict__ v1,
                             float* __restrict__ e1, float* __restrict__ e2,
                             float* __restrict__ bns, float* __restrict__ bnt) {
    int k = blockIdx.x, lane = threadIdx.x;
    float s0 = 0, s1 = 0, d0 = 0, d1 = 0, t0 = 0, t1 = 0;
    for (int c = lane; c < 128; c += 64) {
        s0 += Ws1[k * 256 + c] * as1[c];
        s1 += Ws1[k * 256 + 128 + c] * as1[128 + c];
        d0 += Wd1[k * 256 + c] * ad1[c];
        d1 += Wd1[k * 256 + 128 + c] * ad1[128 + c];
        t0 += Ws2[k * 128 + c] * as2[c];
        t1 += Wd2[k * 128 + c] * ad2[c];
    }
    for (int d = 1; d < 64; d <<= 1) {
        s0 += __shfl_xor(s0, d); s1 += __shfl_xor(s1, d);
        d0 += __shfl_xor(d0, d); d1 += __shfl_xor(d1, d);
        t0 += __shfl_xor(t0, d); t1 += __shfl_xor(t1, d);
    }
    if (lane == 0) {
        e1[k * 4 + 0] = s0; e1[k * 4 + 1] = s1; e1[k * 4 + 2] = d0; e1[k * 4 + 3] = d1;
        e2[k * 2 + 0] = t0; e2[k * 2 + 1] = t1;
        float sc = g1[k] * rsqrtf(v1[k] + 1e-5f);
        bns[k] = sc;
        bnt[k] = (b1[k] - m1[k]) * sc + beta1[k];
    }
}

// ---------------------------------------------------------------- prep2 -----
// fragment-linear B layouts for 32x32x16 MFMA:
// bfl1: [9 nt][16 kb][64 lane][8 j]  (nt 0-7: Ws1 cols; nt 8: e1 pad cols 0-3)
// bfl2: [5 nt][16 kb][64 lane][8 j]  (nt 0-3: Ws2 cols; nt 4: e2 pad cols 0-1)
// element (nt,kb,lane,j): n = nt*32 + (lane&31), k = kb*16 + (lane>>5)*8 + j
__global__ void prep2_kernel(const float* __restrict__ Ws1, const float* __restrict__ Ws2,
                             const float* __restrict__ e1, const float* __restrict__ e2,
                             f16* __restrict__ bfl1, f16* __restrict__ bfl2) {
    int i = blockIdx.x * 256 + threadIdx.x;
    if (i < 73728) {
        int j = i & 7, lane = (i >> 3) & 63, kb = (i >> 9) & 15, nt = i >> 13;
        int c = lane & 31, hi = lane >> 5;
        int k = kb * 16 + hi * 8 + j;
        float v;
        if (nt < 8) v = Ws1[k * 256 + nt * 32 + c];
        else v = (c < 4) ? e1[k * 4 + c] : 0.f;
        bfl1[i] = (f16)v;
    } else {
        int i2 = i - 73728;
        if (i2 < 40960) {
            int j = i2 & 7, lane = (i2 >> 3) & 63, kb = (i2 >> 9) & 15, nt = i2 >> 13;
            int c = lane & 31, hi = lane >> 5;
            int k = kb * 16 + hi * 8 + j;
            float v;
            if (nt < 4) v = Ws2[k * 128 + nt * 32 + c];
            else v = (c < 2) ? e2[k * 2 + c] : 0.f;
            bfl2[i2] = (f16)v;
        }
    }
}

// ---------------------------------------------------------------- gemm1 -----
// hs = f16(x) @ Ws1 -> [N0,256] f16, a_s1[N0][2], a_d1[N1][2] via pad tile (nt8).
// Block: 64 rows, 4 waves = 2 row-tiles x 2 n-groups. ONE barrier per block:
// A staged once to XOR-swizzled LDS [64][256] f16; B-frags stream straight
// from L2 (fragment-linear bfl, 1KB/wave coalesced loads); no K-loop barriers.
__global__ __launch_bounds__(256, 4) void gemm1_kernel(
    const float* __restrict__ x, const f16* __restrict__ bfl,
    f16* __restrict__ hs, float* __restrict__ as_out, float* __restrict__ ad_out) {
    __shared__ __align__(16) unsigned char smA[32768];
    const int t = threadIdx.x;
    const int wave = t >> 6, lane = t & 63;
    const int wr = wave & 1, wg = wave >> 1;
    const int col = lane & 31, hi = lane >> 5;
    const int r0 = blockIdx.x * 64;

    // stage A: thread -> row t>>2, f16-byte range (t&3)*128..+127 of that row
    {
        int arow = t >> 2, q = t & 3;
        int grow = r0 + arow;
        int sw = (arow & 7) << 4;
        const float4* src = (const float4*)(x + (size_t)grow * 256) + q * 16;
        unsigned char* wb = smA + arow * 512;
#pragma unroll
        for (int i = 0; i < 8; i++) {
            float4 a0, a1;
            if (grow < N0C) { a0 = src[2 * i]; a1 = src[2 * i + 1]; }
            else { a0 = make_float4(0.f, 0.f, 0.f, 0.f); a1 = a0; }
            f16x8 v = {(f16)a0.x, (f16)a0.y, (f16)a0.z, (f16)a0.w,
                       (f16)a1.x, (f16)a1.y, (f16)a1.z, (f16)a1.w};
            *(f16x8*)(wb + ((q * 128 + i * 16) ^ sw)) = v;
        }
    }
    __syncthreads();

    const int myrow = wr * 32 + col;
    const int asw = (myrow & 7) << 4;
    const int abase = myrow * 512 + hi * 16;
    const int rbase = r0 + wr * 32 + 4 * hi;

    if (wg == 0) {
        f32x16 acc[5] = {};
        for (int kb = 0; kb < 16; kb++) {
            f16x8 af = *(const f16x8*)(smA + ((abase + kb * 32) ^ asw));
#pragma unroll
            for (int j = 0; j < 5; j++) {
                f16x8 bf = *(const f16x8*)(bfl + ((size_t)(j * 16 + kb) * 64 + lane) * 8);
                acc[j] = __builtin_amdgcn_mfma_f32_32x32x16_f16(af, bf, acc[j], 0, 0, 0);
            }
        }
#pragma unroll
        for (int j = 0; j < 5; j++)
#pragma unroll
            for (int r = 0; r < 16; r++) {
                int grow = rbase + (r & 3) + 8 * (r >> 2);
                if (grow < N0C) hs[(size_t)grow * 256 + j * 32 + col] = (f16)acc[j][r];
            }
    } else {
        f32x16 acc[4] = {};
        for (int kb = 0; kb < 16; kb++) {
            f16x8 af = *(const f16x8*)(smA + ((abase + kb * 32) ^ asw));
#pragma unroll
            for (int j = 0; j < 4; j++) {
                f16x8 bf = *(const f16x8*)(bfl + ((size_t)((5 + j) * 16 + kb) * 64 + lane) * 8);
                acc[j] = __builtin_amdgcn_mfma_f32_32x32x16_f16(af, bf, acc[j], 0, 0, 0);
            }
        }
#pragma unroll
        for (int j = 0; j < 3; j++)
#pragma unroll
            for (int r = 0; r < 16; r++) {
                int grow = rbase + (r & 3) + 8 * (r >> 2);
                if (grow < N0C) hs[(size_t)grow * 256 + (5 + j) * 32 + col] = (f16)acc[j][r];
            }
#pragma unroll
        for (int r = 0; r < 16; r++) {
            int grow = rbase + (r & 3) + 8 * (r >> 2);
            float v = acc[3][r];
            if (col < 2) {
                if (grow < N0C) as_out[grow * 2 + col] = v;
            } else if (col < 4) {
                if (grow < N1C) ad_out[grow * 2 + (col - 2)] = v;
            }
        }
    }
}

// ---------------------------------------------------------------- gemm2 -----
// hs2 = h @ Ws2 -> [N1,128] f16, a_s2[N1], a_d2[N2] via pad tile (nt4).
// Same skeleton; A is already f16 (direct 16B copies to swizzled LDS).
__global__ __launch_bounds__(256, 4) void gemm2_kernel(
    const f16* __restrict__ h, const f16* __restrict__ bfl,
    f16* __restrict__ hs2, float* __restrict__ as_out, float* __restrict__ ad_out) {
    __shared__ __align__(16) unsigned char smA[32768];
    const int t = threadIdx.x;
    const int wave = t >> 6, lane = t & 63;
    const int wr = wave & 1, wg = wave >> 1;
    const int col = lane & 31, hi = lane >> 5;
    const int r0 = blockIdx.x * 64;

    {
        int arow = t >> 2, q = t & 3;
        int grow = r0 + arow;
        int sw = (arow & 7) << 4;
        const unsigned char* src = (const unsigned char*)(h + (size_t)grow * 256) + q * 128;
        unsigned char* wb = smA + arow * 512;
#pragma unroll
        for (int i = 0; i < 8; i++) {
            int4 v;
            if (grow < N1C) v = *(const int4*)(src + i * 16);
            else v = make_int4(0, 0, 0, 0);
            *(int4*)(wb + ((q * 128 + i * 16) ^ sw)) = v;
        }
    }
    __syncthreads();

    const int myrow = wr * 32 + col;
    const int asw = (myrow & 7) << 4;
    const int abase = myrow * 512 + hi * 16;
    const int rbase = r0 + wr * 32 + 4 * hi;

    if (wg == 0) {
        f32x16 acc[3] = {};
        for (int kb = 0; kb < 16; kb++) {
            f16x8 af = *(const f16x8*)(smA + ((abase + kb * 32) ^ asw));
#pragma unroll
            for (int j = 0; j < 3; j++) {
                f16x8 bf = *(const f16x8*)(bfl + ((size_t)(j * 16 + kb) * 64 + lane) * 8);
                acc[j] = __builtin_amdgcn_mfma_f32_32x32x16_f16(af, bf, acc[j], 0, 0, 0);
            }
        }
#pragma unroll
        for (int j = 0; j < 3; j++)
#pragma unroll
            for (int r = 0; r < 16; r++) {
                int grow = rbase + (r & 3) + 8 * (r >> 2);
                if (grow < N1C) hs2[(size_t)grow * 128 + j * 32 + col] = (f16)acc[j][r];
            }
    } else {
        f32x16 acc[2] = {};
        for (int kb = 0; kb < 16; kb++) {
            f16x8 af = *(const f16x8*)(smA + ((abase + kb * 32) ^ asw));
#pragma unroll
            for (int j = 0; j < 2; j++) {
                f16x8 bf = *(const f16x8*)(bfl + ((size_t)((3 + j) * 16 + kb) * 64 + lane) * 8);
                acc[j] = __builtin_amdgcn_mfma_f32_32x32x16_f16(af, bf, acc[j], 0, 0, 0);
            }
        }
#pragma unroll
        for (int r = 0; r < 16; r++) {
            int grow = rbase + (r & 3) + 8 * (r >> 2);
            if (grow < N1C) hs2[(size_t)grow * 128 + 3 * 32 + col] = (f16)acc[0][r];
        }
#pragma unroll
        for (int r = 0; r < 16; r++) {
            int grow = rbase + (r & 3) + 8 * (r >> 2);
            float v = acc[1][r];
            if (col == 0) {
                if (grow < N1C) as_out[grow] = v;
            } else if (col == 1) {
                if (grow < N2C) ad_out[grow] = v;
            }
        }
    }
}

// ---------------------------------------------------------------- agg1 ------
// one wave per dst node: masked edge softmax (heads=2) + gather-accumulate
// + fused bias/BN/leaky_relu(0.01), writes h [N1,256] f16
__global__ void agg1_kernel(const int* __restrict__ col1, const int* __restrict__ t1,
                            const int* __restrict__ timep, const int* __restrict__ intervalp,
                            const float* __restrict__ a_s, const float* __restrict__ a_d,
                            const f16* __restrict__ hs,
                            const float* __restrict__ bns, const float* __restrict__ bnt,
                            f16* __restrict__ h) {
    int wid = (blockIdx.x * blockDim.x + threadIdx.x) >> 6;
    if (wid >= N1C) return;
    int lane = threadIdx.x & 63;
    int T = timep[0], I = intervalp[0];
    int j = lane & 15;
    int c = col1[wid * 16 + j];
    int tv = t1[wid * 16 + j];
    bool mk = (tv >= T) && (tv < T + I);
    float e0 = -INFINITY, e1 = -INFINITY;
    if (mk) {
        float s0 = a_s[c * 2 + 0] + a_d[wid * 2 + 0];
        float s1 = a_s[c * 2 + 1] + a_d[wid * 2 + 1];
        e0 = s0 > 0.f ? s0 : 0.2f * s0;
        e1 = s1 > 0.f ? s1 : 0.2f * s1;
    }
    float m0 = e0, m1 = e1;
#pragma unroll
    for (int d = 1; d < 16; d <<= 1) {
        m0 = fmaxf(m0, __shfl_xor(m0, d));
        m1 = fmaxf(m1, __shfl_xor(m1, d));
    }
    float ex0 = mk ? __expf(e0 - m0) : 0.f;
    float ex1 = mk ? __expf(e1 - m1) : 0.f;
    float s0 = ex0, s1 = ex1;
#pragma unroll
    for (int d = 1; d < 16; d <<= 1) {
        s0 += __shfl_xor(s0, d);
        s1 += __shfl_xor(s1, d);
    }
    float r0 = 1.f / fmaxf(s0, 1e-16f);
    float r1 = 1.f / fmaxf(s1, 1e-16f);
    unsigned long long mb = __ballot(mk) & 0xFFFFull;
    int head = lane >> 5;
    float rden = head ? r1 : r0;
    float acc0 = 0.f, acc1 = 0.f, acc2 = 0.f, acc3 = 0.f;
    while (mb) {
        int jj = __builtin_ctzll(mb);
        mb &= mb - 1;
        int cj = __shfl(c, jj);
        float w0 = __shfl(ex0, jj), w1 = __shfl(ex1, jj);
        float w = (head ? w1 : w0) * rden;
        f16x4 v = *(const f16x4*)(hs + (size_t)cj * 256 + lane * 4);
        acc0 += w * (float)v[0];
        acc1 += w * (float)v[1];
        acc2 += w * (float)v[2];
        acc3 += w * (float)v[3];
    }
    int cb = lane * 4;
    float4 sc = *(const float4*)(bns + cb);
    float4 sh = *(const float4*)(bnt + cb);
    float o0 = acc0 * sc.x + sh.x; o0 = o0 > 0.f ? o0 : 0.01f * o0;
    float o1 = acc1 * sc.y + sh.y; o1 = o1 > 0.f ? o1 : 0.01f * o1;
    float o2 = acc2 * sc.z + sh.z; o2 = o2 > 0.f ? o2 : 0.01f * o2;
    float o3 = acc3 * sc.w + sh.w; o3 = o3 > 0.f ? o3 : 0.01f * o3;
    f16x4 ov = {(f16)o0, (f16)o1, (f16)o2, (f16)o3};
    *(f16x4*)(h + (size_t)wid * 256 + cb) = ov;
}

// ---------------------------------------------------------------- agg2 ------
// one wave per dst: masked softmax (1 head), gather [N1,128] f16, + b2, f32 out
__global__ void agg2_kernel(const int* __restrict__ col2, const int* __restrict__ t2,
                            const int* __restrict__ timep, const int* __restrict__ intervalp,
                            const float* __restrict__ a_s, const float* __restrict__ a_d,
                            const f16* __restrict__ hs2,
                            const float* __restrict__ b2, float* __restrict__ out) {
    int wid = (blockIdx.x * blockDim.x + threadIdx.x) >> 6;
    if (wid >= N2C) return;
    int lane = threadIdx.x & 63;
    int T = timep[0], I = intervalp[0];
    int j = lane & 15;
    int c = col2[wid * 16 + j];
    int tv = t2[wid * 16 + j];
    bool mk = (tv >= T) && (tv < T + I);
    float e = -INFINITY;
    if (mk) {
        float s = a_s[c] + a_d[wid];
        e = s > 0.f ? s : 0.2f * s;
    }
    float m = e;
#pragma unroll
    for (int d = 1; d < 16; d <<= 1) m = fmaxf(m, __shfl_xor(m, d));
    float ex = mk ? __expf(e - m) : 0.f;
    float s = ex;
#pragma unroll
    for (int d = 1; d < 16; d <<= 1) s += __shfl_xor(s, d);
    float r = 1.f / fmaxf(s, 1e-16f);
    unsigned long long mb = __ballot(mk) & 0xFFFFull;
    float acc0 = 0.f, acc1 = 0.f;
    while (mb) {
        int jj = __builtin_ctzll(mb);
        mb &= mb - 1;
        int cj = __shfl(c, jj);
        float w = __shfl(ex, jj) * r;
        f16x2 v = *(const f16x2*)(hs2 + (size_t)cj * 128 + lane * 2);
        acc0 += w * (float)v[0];
        acc1 += w * (float)v[1];
    }
    float2 o = make_float2(acc0 + b2[lane * 2], acc1 + b2[lane * 2 + 1]);
    *(float2*)(out + (size_t)wid * 128 + lane * 2) = o;
}

// ---------------------------------------------------------------- launch ----
extern "C" void kernel_launch(void* const* d_in, const int* in_sizes, int n_in,
                              void* d_out, int out_size, void* d_ws, size_t ws_size,
                              hipStream_t stream) {
    const float* x = (const float*)d_in[0];
    const int* col1 = (const int*)d_in[2];
    const int* t1 = (const int*)d_in[3];
    const int* col2 = (const int*)d_in[5];
    const int* t2 = (const int*)d_in[6];
    const int* timep = (const int*)d_in[7];
    const int* intervalp = (const int*)d_in[8];
    const float* Ws1 = (const float*)d_in[9];
    const float* Wd1 = (const float*)d_in[10];
    const float* as1 = (const float*)d_in[11];
    const float* ad1 = (const float*)d_in[12];
    const float* b1 = (const float*)d_in[13];
    const float* g1 = (const float*)d_in[14];
    const float* beta1 = (const float*)d_in[15];
    const float* m1 = (const float*)d_in[16];
    const float* v1 = (const float*)d_in[17];
    const float* Ws2 = (const float*)d_in[18];
    const float* Wd2 = (const float*)d_in[19];
    const float* as2 = (const float*)d_in[20];
    const float* ad2 = (const float*)d_in[21];
    const float* b2 = (const float*)d_in[22];
    float* out = (float*)d_out;

    char* ws = (char*)d_ws;
    size_t off = 0;
    auto alloc = [&](size_t bytes) {
        size_t o = off;
        off += (bytes + 511) & ~(size_t)511;
        return o;
    };
    f16* hs = (f16*)(ws + alloc((size_t)N0C * 256 * 2));
    f16* h = (f16*)(ws + alloc((size_t)N1C * 256 * 2));
    f16* hs2 = (f16*)(ws + alloc((size_t)N1C * 128 * 2));
    float* a_s1 = (float*)(ws + alloc((size_t)N0C * 2 * 4));
    float* a_d1 = (float*)(ws + alloc((size_t)N1C * 2 * 4));
    float* a_s2 = (float*)(ws + alloc((size_t)N1C * 4));
    float* a_d2 = (float*)(ws + alloc((size_t)N2C * 4));
    f16* bfl1 = (f16*)(ws + alloc((size_t)73728 * 2));
    f16* bfl2 = (f16*)(ws + alloc((size_t)40960 * 2));
    float* e1 = (float*)(ws + alloc(1024 * 4));
    float* e2 = (float*)(ws + alloc(512 * 4));
    float* bns = (float*)(ws + alloc(256 * 4));
    float* bnt = (float*)(ws + alloc(256 * 4));

    prep1_kernel<<<256, 64, 0, stream>>>(Ws1, Wd1, as1, ad1, Ws2, Wd2, as2, ad2,
                                         b1, g1, beta1, m1, v1, e1, e2, bns, bnt);
    prep2_kernel<<<448, 256, 0, stream>>>(Ws1, Ws2, e1, e2, bfl1, bfl2);
    gemm1_kernel<<<(N0C + 63) / 64, 256, 0, stream>>>(x, bfl1, hs, a_s1, a_d1);
    agg1_kernel<<<N1C / 4, 256, 0, stream>>>(col1, t1, timep, intervalp,
                                             a_s1, a_d1, hs, bns, bnt, h);
    gemm2_kernel<<<(N1C + 63) / 64, 256, 0, stream>>>(h, bfl2, hs2, a_s2, a_d2);
    agg2_kernel<<<N2C / 4, 256, 0, stream>>>(col2, t2, timep, intervalp,
                                             a_s2, a_d2, hs2, b2, out);
}

// Round 6
// 112.617 us; speedup vs baseline: 1.1707x; 1.1707x over previous
//
#include <hip/hip_runtime.h>
#include <hip/hip_bf16.h>

#define N0C 100000
#define N1C 50000
#define N2C 25000

typedef _Float16 f16;
typedef _Float16 f16x2 __attribute__((ext_vector_type(2)));
typedef _Float16 f16x4 __attribute__((ext_vector_type(4)));
typedef _Float16 f16x8 __attribute__((ext_vector_type(8)));
typedef float f32x16 __attribute__((ext_vector_type(16)));

// ---------------------------------------------------------------- prep1 -----
// e1[k][4] = {Ws1[:,0:128]@as1_h0, Ws1[:,128:]@as1_h1, Wd1[:,0:128]@ad1_h0, Wd1[:,128:]@ad1_h1}
// e2[k][2] = {Ws2@as2, Wd2@ad2};  bns/bnt = folded BN scale/shift
__global__ void prep1_kernel(const float* __restrict__ Ws1, const float* __restrict__ Wd1,
                             const float* __restrict__ as1, const float* __restrict__ ad1,
                             const float* __restrict__ Ws2, const float* __restrict__ Wd2,
                             const float* __restrict__ as2, const float* __restrict__ ad2,
                             const float* __restrict__ b1, const float* __restrict__ g1,
                             const float* __restrict__ beta1, const float* __restrict__ m1,
                             const float* __restrict__ v1,
                             float* __restrict__ e1, float* __restrict__ e2,
                             float* __restrict__ bns, float* __restrict__ bnt) {
    int k = blockIdx.x, lane = threadIdx.x;
    float s0 = 0, s1 = 0, d0 = 0, d1 = 0, t0 = 0, t1 = 0;
    for (int c = lane; c < 128; c += 64) {
        s0 += Ws1[k * 256 + c] * as1[c];
        s1 += Ws1[k * 256 + 128 + c] * as1[128 + c];
        d0 += Wd1[k * 256 + c] * ad1[c];
        d1 += Wd1[k * 256 + 128 + c] * ad1[128 + c];
        t0 += Ws2[k * 128 + c] * as2[c];
        t1 += Wd2[k * 128 + c] * ad2[c];
    }
    for (int d = 1; d < 64; d <<= 1) {
        s0 += __shfl_xor(s0, d); s1 += __shfl_xor(s1, d);
        d0 += __shfl_xor(d0, d); d1 += __shfl_xor(d1, d);
        t0 += __shfl_xor(t0, d); t1 += __shfl_xor(t1, d);
    }
    if (lane == 0) {
        e1[k * 4 + 0] = s0; e1[k * 4 + 1] = s1; e1[k * 4 + 2] = d0; e1[k * 4 + 3] = d1;
        e2[k * 2 + 0] = t0; e2[k * 2 + 1] = t1;
        float sc = g1[k] * rsqrtf(v1[k] + 1e-5f);
        bns[k] = sc;
        bnt[k] = (b1[k] - m1[k]) * sc + beta1[k];
    }
}

// ---------------------------------------------------------------- prep2 -----
// fragment-linear B layouts for 32x32x16 MFMA:
// bfl1: [9 nt][16 kb][64 lane][8 j]  (nt 0-7: Ws1 cols; nt 8: e1 pad cols 0-3)
// bfl2: [5 nt][16 kb][64 lane][8 j]  (nt 0-3: Ws2 cols; nt 4: e2 pad cols 0-1)
// element (nt,kb,lane,j): n = nt*32 + (lane&31), k = kb*16 + (lane>>5)*8 + j
__global__ void prep2_kernel(const float* __restrict__ Ws1, const float* __restrict__ Ws2,
                             const float* __restrict__ e1, const float* __restrict__ e2,
                             f16* __restrict__ bfl1, f16* __restrict__ bfl2) {
    int i = blockIdx.x * 256 + threadIdx.x;
    if (i < 73728) {
        int j = i & 7, lane = (i >> 3) & 63, kb = (i >> 9) & 15, nt = i >> 13;
        int c = lane & 31, hi = lane >> 5;
        int k = kb * 16 + hi * 8 + j;
        float v;
        if (nt < 8) v = Ws1[k * 256 + nt * 32 + c];
        else v = (c < 4) ? e1[k * 4 + c] : 0.f;
        bfl1[i] = (f16)v;
    } else {
        int i2 = i - 73728;
        if (i2 < 40960) {
            int j = i2 & 7, lane = (i2 >> 3) & 63, kb = (i2 >> 9) & 15, nt = i2 >> 13;
            int c = lane & 31, hi = lane >> 5;
            int k = kb * 16 + hi * 8 + j;
            float v;
            if (nt < 4) v = Ws2[k * 128 + nt * 32 + c];
            else v = (c < 2) ? e2[k * 2 + c] : 0.f;
            bfl2[i2] = (f16)v;
        }
    }
}

// ---------------------------------------------------------------- gemm1 -----
// hs = f16(x) @ Ws1 -> [N0,256] f16 + a_s1/a_d1 via pad tile (nt8).
// Block: 64 rows x 288 cols, 9 waves; wave w owns nt=w (32 cols) x 64 rows.
// acc = 2x f32x16 (32 AGPR). B: 16 frags from L2-resident bfl, 8-at-a-time in
// registers. A: staged ONCE to fragment-linear XOR-swizzled LDS
// [rt][kb][lane][16B]^((kb&7)<<4); one barrier total, conflict-free both sides.
__global__ __launch_bounds__(576, 5) void gemm1_kernel(
    const float* __restrict__ x, const f16* __restrict__ bfl,
    f16* __restrict__ hs, float* __restrict__ as_out, float* __restrict__ ad_out) {
    __shared__ __align__(16) unsigned char smA[32768];
    const int t = threadIdx.x;
    const int wave = t / 64, lane = t & 63;
    const int col = lane & 31, hi = lane >> 5;
    const int r0 = blockIdx.x * 64;

    // stage A: 512 threads, 8 threads/row, 128B (32 f32) each -> 4 swizzled b128
    if (t < 512) {
        int row = t >> 3, seg = t & 7;
        int grow = r0 + row;
        int rt = row >> 5, rl = row & 31;
        const float4* src = (const float4*)(x + (size_t)grow * 256 + seg * 32);
        f16x8 v[4];
        if (grow < N0C) {
#pragma unroll
            for (int p = 0; p < 4; p++) {
                float4 a0 = src[2 * p], a1 = src[2 * p + 1];
                v[p] = (f16x8){(f16)a0.x, (f16)a0.y, (f16)a0.z, (f16)a0.w,
                               (f16)a1.x, (f16)a1.y, (f16)a1.z, (f16)a1.w};
            }
        } else {
#pragma unroll
            for (int p = 0; p < 4; p++) v[p] = (f16x8){0, 0, 0, 0, 0, 0, 0, 0};
        }
#pragma unroll
        for (int p = 0; p < 4; p++) {
            int kb = seg * 2 + (p >> 1);
            int ln = rl + 32 * (p & 1);
            int addr = (((rt * 16 + kb) * 64 + ln) * 16) ^ ((kb & 7) << 4);
            *(f16x8*)(smA + addr) = v[p];
        }
    }
    __syncthreads();

    const int nt = wave;  // 0..8
    const f16* bbase = bfl + (size_t)nt * 16 * 64 * 8 + lane * 8;
    f32x16 acc0 = {}, acc1 = {};
    f16x8 b[8];

    // half 0: kb 0..7
#pragma unroll
    for (int kb = 0; kb < 8; kb++) b[kb] = *(const f16x8*)(bbase + (size_t)kb * 512);
#pragma unroll
    for (int kb = 0; kb < 8; kb++) {
        f16x8 a0 = *(const f16x8*)(smA + (((0 * 16 + kb) * 64 + lane) * 16 ^ ((kb & 7) << 4)));
        f16x8 a1 = *(const f16x8*)(smA + (((1 * 16 + kb) * 64 + lane) * 16 ^ ((kb & 7) << 4)));
        acc0 = __builtin_amdgcn_mfma_f32_32x32x16_f16(a0, b[kb], acc0, 0, 0, 0);
        acc1 = __builtin_amdgcn_mfma_f32_32x32x16_f16(a1, b[kb], acc1, 0, 0, 0);
    }
    // half 1: kb 8..15
#pragma unroll
    for (int kb = 8; kb < 16; kb++) b[kb - 8] = *(const f16x8*)(bbase + (size_t)kb * 512);
#pragma unroll
    for (int kb = 8; kb < 16; kb++) {
        f16x8 a0 = *(const f16x8*)(smA + (((0 * 16 + kb) * 64 + lane) * 16 ^ ((kb & 7) << 4)));
        f16x8 a1 = *(const f16x8*)(smA + (((1 * 16 + kb) * 64 + lane) * 16 ^ ((kb & 7) << 4)));
        acc0 = __builtin_amdgcn_mfma_f32_32x32x16_f16(a0, b[kb - 8], acc0, 0, 0, 0);
        acc1 = __builtin_amdgcn_mfma_f32_32x32x16_f16(a1, b[kb - 8], acc1, 0, 0, 0);
    }

    // epilogue: C/D layout col=lane&31, row=(r&3)+8*(r>>2)+4*hi
    if (nt < 8) {
#pragma unroll
        for (int r = 0; r < 16; r++) {
            int grow = r0 + (r & 3) + 8 * (r >> 2) + 4 * hi;
            if (grow < N0C) hs[(size_t)grow * 256 + nt * 32 + col] = (f16)acc0[r];
        }
#pragma unroll
        for (int r = 0; r < 16; r++) {
            int grow = r0 + 32 + (r & 3) + 8 * (r >> 2) + 4 * hi;
            if (grow < N0C) hs[(size_t)grow * 256 + nt * 32 + col] = (f16)acc1[r];
        }
    } else {
#pragma unroll
        for (int r = 0; r < 16; r++) {
            int grow = r0 + (r & 3) + 8 * (r >> 2) + 4 * hi;
            float v0 = acc0[r];
            int grow1 = grow + 32;
            float v1 = acc1[r];
            if (col < 2) {
                if (grow < N0C) as_out[grow * 2 + col] = v0;
                if (grow1 < N0C) as_out[grow1 * 2 + col] = v1;
            } else if (col < 4) {
                if (grow < N1C) ad_out[grow * 2 + (col - 2)] = v0;
                if (grow1 < N1C) ad_out[grow1 * 2 + (col - 2)] = v1;
            }
        }
    }
}

// ---------------------------------------------------------------- gemm2 -----
// hs2 = h @ Ws2 -> [N1,128] f16 + a_s2/a_d2 via pad tile (nt4).
// Same skeleton: 5 waves, 64 rows/block, A (f16) staged to swizzled frag-LDS.
__global__ __launch_bounds__(320, 5) void gemm2_kernel(
    const f16* __restrict__ h, const f16* __restrict__ bfl,
    f16* __restrict__ hs2, float* __restrict__ as_out, float* __restrict__ ad_out) {
    __shared__ __align__(16) unsigned char smA[32768];
    const int t = threadIdx.x;
    const int wave = t / 64, lane = t & 63;
    const int col = lane & 31, hi = lane >> 5;
    const int r0 = blockIdx.x * 64;

    // stage A: 256 threads, 4 threads/row, 128B (64 f16) each -> 8 swizzled b128
    if (t < 256) {
        int row = t >> 2, seg = t & 3;
        int grow = r0 + row;
        int rt = row >> 5, rl = row & 31;
        const int4* src = (const int4*)(h + (size_t)grow * 256 + seg * 64);
#pragma unroll
        for (int q = 0; q < 8; q++) {
            int4 v;
            if (grow < N1C) v = src[q];
            else v = make_int4(0, 0, 0, 0);
            int kb = seg * 4 + (q >> 1);
            int ln = rl + 32 * (q & 1);
            int addr = (((rt * 16 + kb) * 64 + ln) * 16) ^ ((kb & 7) << 4);
            *(int4*)(smA + addr) = v;
        }
    }
    __syncthreads();

    const int nt = wave;  // 0..4
    const f16* bbase = bfl + (size_t)nt * 16 * 64 * 8 + lane * 8;
    f32x16 acc0 = {}, acc1 = {};
    f16x8 b[8];

#pragma unroll
    for (int kb = 0; kb < 8; kb++) b[kb] = *(const f16x8*)(bbase + (size_t)kb * 512);
#pragma unroll
    for (int kb = 0; kb < 8; kb++) {
        f16x8 a0 = *(const f16x8*)(smA + (((0 * 16 + kb) * 64 + lane) * 16 ^ ((kb & 7) << 4)));
        f16x8 a1 = *(const f16x8*)(smA + (((1 * 16 + kb) * 64 + lane) * 16 ^ ((kb & 7) << 4)));
        acc0 = __builtin_amdgcn_mfma_f32_32x32x16_f16(a0, b[kb], acc0, 0, 0, 0);
        acc1 = __builtin_amdgcn_mfma_f32_32x32x16_f16(a1, b[kb], acc1, 0, 0, 0);
    }
#pragma unroll
    for (int kb = 8; kb < 16; kb++) b[kb - 8] = *(const f16x8*)(bbase + (size_t)kb * 512);
#pragma unroll
    for (int kb = 8; kb < 16; kb++) {
        f16x8 a0 = *(const f16x8*)(smA + (((0 * 16 + kb) * 64 + lane) * 16 ^ ((kb & 7) << 4)));
        f16x8 a1 = *(const f16x8*)(smA + (((1 * 16 + kb) * 64 + lane) * 16 ^ ((kb & 7) << 4)));
        acc0 = __builtin_amdgcn_mfma_f32_32x32x16_f16(a0, b[kb - 8], acc0, 0, 0, 0);
        acc1 = __builtin_amdgcn_mfma_f32_32x32x16_f16(a1, b[kb - 8], acc1, 0, 0, 0);
    }

    if (nt < 4) {
#pragma unroll
        for (int r = 0; r < 16; r++) {
            int grow = r0 + (r & 3) + 8 * (r >> 2) + 4 * hi;
            if (grow < N1C) hs2[(size_t)grow * 128 + nt * 32 + col] = (f16)acc0[r];
        }
#pragma unroll
        for (int r = 0; r < 16; r++) {
            int grow = r0 + 32 + (r & 3) + 8 * (r >> 2) + 4 * hi;
            if (grow < N1C) hs2[(size_t)grow * 128 + nt * 32 + col] = (f16)acc1[r];
        }
    } else {
#pragma unroll
        for (int r = 0; r < 16; r++) {
            int grow = r0 + (r & 3) + 8 * (r >> 2) + 4 * hi;
            int grow1 = grow + 32;
            float v0 = acc0[r], v1 = acc1[r];
            if (col == 0) {
                if (grow < N1C) as_out[grow] = v0;
                if (grow1 < N1C) as_out[grow1] = v1;
            } else if (col == 1) {
                if (grow < N2C) ad_out[grow] = v0;
                if (grow1 < N2C) ad_out[grow1] = v1;
            }
        }
    }
}

// ---------------------------------------------------------------- agg1 ------
// one wave per dst node: masked edge softmax (heads=2) + gather-accumulate
// + fused bias/BN/leaky_relu(0.01), writes h [N1,256] f16
__global__ void agg1_kernel(const int* __restrict__ col1, const int* __restrict__ t1,
                            const int* __restrict__ timep, const int* __restrict__ intervalp,
                            const float* __restrict__ a_s, const float* __restrict__ a_d,
                            const f16* __restrict__ hs,
                            const float* __restrict__ bns, const float* __restrict__ bnt,
                            f16* __restrict__ h) {
    int wid = (blockIdx.x * blockDim.x + threadIdx.x) >> 6;
    if (wid >= N1C) return;
    int lane = threadIdx.x & 63;
    int T = timep[0], I = intervalp[0];
    int j = lane & 15;
    int c = col1[wid * 16 + j];
    int tv = t1[wid * 16 + j];
    bool mk = (tv >= T) && (tv < T + I);
    float e0 = -INFINITY, e1 = -INFINITY;
    if (mk) {
        float s0 = a_s[c * 2 + 0] + a_d[wid * 2 + 0];
        float s1 = a_s[c * 2 + 1] + a_d[wid * 2 + 1];
        e0 = s0 > 0.f ? s0 : 0.2f * s0;
        e1 = s1 > 0.f ? s1 : 0.2f * s1;
    }
    float m0 = e0, m1 = e1;
#pragma unroll
    for (int d = 1; d < 16; d <<= 1) {
        m0 = fmaxf(m0, __shfl_xor(m0, d));
        m1 = fmaxf(m1, __shfl_xor(m1, d));
    }
    float ex0 = mk ? __expf(e0 - m0) : 0.f;
    float ex1 = mk ? __expf(e1 - m1) : 0.f;
    float s0 = ex0, s1 = ex1;
#pragma unroll
    for (int d = 1; d < 16; d <<= 1) {
        s0 += __shfl_xor(s0, d);
        s1 += __shfl_xor(s1, d);
    }
    float r0 = 1.f / fmaxf(s0, 1e-16f);
    float r1 = 1.f / fmaxf(s1, 1e-16f);
    unsigned long long mb = __ballot(mk) & 0xFFFFull;
    int head = lane >> 5;
    float rden = head ? r1 : r0;
    float acc0 = 0.f, acc1 = 0.f, acc2 = 0.f, acc3 = 0.f;
    while (mb) {
        int jj = __builtin_ctzll(mb);
        mb &= mb - 1;
        int cj = __shfl(c, jj);
        float w0 = __shfl(ex0, jj), w1 = __shfl(ex1, jj);
        float w = (head ? w1 : w0) * rden;
        f16x4 v = *(const f16x4*)(hs + (size_t)cj * 256 + lane * 4);
        acc0 += w * (float)v[0];
        acc1 += w * (float)v[1];
        acc2 += w * (float)v[2];
        acc3 += w * (float)v[3];
    }
    int cb = lane * 4;
    float4 sc = *(const float4*)(bns + cb);
    float4 sh = *(const float4*)(bnt + cb);
    float o0 = acc0 * sc.x + sh.x; o0 = o0 > 0.f ? o0 : 0.01f * o0;
    float o1 = acc1 * sc.y + sh.y; o1 = o1 > 0.f ? o1 : 0.01f * o1;
    float o2 = acc2 * sc.z + sh.z; o2 = o2 > 0.f ? o2 : 0.01f * o2;
    float o3 = acc3 * sc.w + sh.w; o3 = o3 > 0.f ? o3 : 0.01f * o3;
    f16x4 ov = {(f16)o0, (f16)o1, (f16)o2, (f16)o3};
    *(f16x4*)(h + (size_t)wid * 256 + cb) = ov;
}

// ---------------------------------------------------------------- agg2 ------
// one wave per dst: masked softmax (1 head), gather [N1,128] f16, + b2, f32 out
__global__ void agg2_kernel(const int* __restrict__ col2, const int* __restrict__ t2,
                            const int* __restrict__ timep, const int* __restrict__ intervalp,
                            const float* __restrict__ a_s, const float* __restrict__ a_d,
                            const f16* __restrict__ hs2,
                            const float* __restrict__ b2, float* __restrict__ out) {
    int wid = (blockIdx.x * blockDim.x + threadIdx.x) >> 6;
    if (wid >= N2C) return;
    int lane = threadIdx.x & 63;
    int T = timep[0], I = intervalp[0];
    int j = lane & 15;
    int c = col2[wid * 16 + j];
    int tv = t2[wid * 16 + j];
    bool mk = (tv >= T) && (tv < T + I);
    float e = -INFINITY;
    if (mk) {
        float s = a_s[c] + a_d[wid];
        e = s > 0.f ? s : 0.2f * s;
    }
    float m = e;
#pragma unroll
    for (int d = 1; d < 16; d <<= 1) m = fmaxf(m, __shfl_xor(m, d));
    float ex = mk ? __expf(e - m) : 0.f;
    float s = ex;
#pragma unroll
    for (int d = 1; d < 16; d <<= 1) s += __shfl_xor(s, d);
    float r = 1.f / fmaxf(s, 1e-16f);
    unsigned long long mb = __ballot(mk) & 0xFFFFull;
    float acc0 = 0.f, acc1 = 0.f;
    while (mb) {
        int jj = __builtin_ctzll(mb);
        mb &= mb - 1;
        int cj = __shfl(c, jj);
        float w = __shfl(ex, jj) * r;
        f16x2 v = *(const f16x2*)(hs2 + (size_t)cj * 128 + lane * 2);
        acc0 += w * (float)v[0];
        acc1 += w * (float)v[1];
    }
    float2 o = make_float2(acc0 + b2[lane * 2], acc1 + b2[lane * 2 + 1]);
    *(float2*)(out + (size_t)wid * 128 + lane * 2) = o;
}

// ---------------------------------------------------------------- launch ----
extern "C" void kernel_launch(void* const* d_in, const int* in_sizes, int n_in,
                              void* d_out, int out_size, void* d_ws, size_t ws_size,
                              hipStream_t stream) {
    const float* x = (const float*)d_in[0];
    const int* col1 = (const int*)d_in[2];
    const int* t1 = (const int*)d_in[3];
    const int* col2 = (const int*)d_in[5];
    const int* t2 = (const int*)d_in[6];
    const int* timep = (const int*)d_in[7];
    const int* intervalp = (const int*)d_in[8];
    const float* Ws1 = (const float*)d_in[9];
    const float* Wd1 = (const float*)d_in[10];
    const float* as1 = (const float*)d_in[11];
    const float* ad1 = (const float*)d_in[12];
    const float* b1 = (const float*)d_in[13];
    const float* g1 = (const float*)d_in[14];
    const float* beta1 = (const float*)d_in[15];
    const float* m1 = (const float*)d_in[16];
    const float* v1 = (const float*)d_in[17];
    const float* Ws2 = (const float*)d_in[18];
    const float* Wd2 = (const float*)d_in[19];
    const float* as2 = (const float*)d_in[20];
    const float* ad2 = (const float*)d_in[21];
    const float* b2 = (const float*)d_in[22];
    float* out = (float*)d_out;

    char* ws = (char*)d_ws;
    size_t off = 0;
    auto alloc = [&](size_t bytes) {
        size_t o = off;
        off += (bytes + 511) & ~(size_t)511;
        return o;
    };
    f16* hs = (f16*)(ws + alloc((size_t)N0C * 256 * 2));
    f16* h = (f16*)(ws + alloc((size_t)N1C * 256 * 2));
    f16* hs2 = (f16*)(ws + alloc((size_t)N1C * 128 * 2));
    float* a_s1 = (float*)(ws + alloc((size_t)N0C * 2 * 4));
    float* a_d1 = (float*)(ws + alloc((size_t)N1C * 2 * 4));
    float* a_s2 = (float*)(ws + alloc((size_t)N1C * 4));
    float* a_d2 = (float*)(ws + alloc((size_t)N2C * 4));
    f16* bfl1 = (f16*)(ws + alloc((size_t)73728 * 2));
    f16* bfl2 = (f16*)(ws + alloc((size_t)40960 * 2));
    float* e1 = (float*)(ws + alloc(1024 * 4));
    float* e2 = (float*)(ws + alloc(512 * 4));
    float* bns = (float*)(ws + alloc(256 * 4));
    float* bnt = (float*)(ws + alloc(256 * 4));

    prep1_kernel<<<256, 64, 0, stream>>>(Ws1, Wd1, as1, ad1, Ws2, Wd2, as2, ad2,
                                         b1, g1, beta1, m1, v1, e1, e2, bns, bnt);
    prep2_kernel<<<448, 256, 0, stream>>>(Ws1, Ws2, e1, e2, bfl1, bfl2);
    gemm1_kernel<<<(N0C + 63) / 64, 576, 0, stream>>>(x, bfl1, hs, a_s1, a_d1);
    agg1_kernel<<<N1C / 4, 256, 0, stream>>>(col1, t1, timep, intervalp,
                                             a_s1, a_d1, hs, bns, bnt, h);
    gemm2_kernel<<<(N1C + 63) / 64, 320, 0, stream>>>(h, bfl2, hs2, a_s2, a_d2);
    agg2_kernel<<<N2C / 4, 256, 0, stream>>>(col2, t2, timep, intervalp,
                                             a_s2, a_d2, hs2, b2, out);
}